// Round 27
// baseline (283.646 us; speedup 1.0000x reference)
//
#include <hip/hip_runtime.h>
#include <hip/hip_bf16.h>
#include <math.h>

#define R_TOT 16384   // B*T
#define DIN   1024    // D
#define DC    256     // Dc
#define KCB   8192    // K codebook entries
#define DSPLIT 8
#define SPLITK (KCB/DSPLIT)   // 1024 codes per split
#define NT (SPLITK/64)        // 16 tiles of 64 codes
#define NG (NT/2)             // 8 groups of 2 tiles
#define MARGIN 0.0085f        // hard bound 2*delta_bf16 = 0.0079; +slack
#define PRUNE  0.0105f        // 0.0079 + bf16 value-store err 0.002 + slack
#define GCAP 64
#define MLMAX 8192

typedef __attribute__((ext_vector_type(8))) short bf16x8;
typedef __attribute__((ext_vector_type(4))) float f32x4;

// ws layout (float offsets)
#define WS_CN    0u          // code_norm f32 8192*256
#define WS_ZN    2097152u    // z_norm f32 16384*256
#define WS_C2    6291456u    // |c|^2 8192
#define WS_CODES 6299648u    // codes int 16384
#define WS_PART  6316032u    // loss partials 512
#define WS_CBF   6316544u    // code_norm bf16 (1048576 f)
#define WS_ZBF   7365120u    // z_norm bf16 (2097152 f)
#define WS_WH    9462272u    // w_z hi bf16 (131072 f); REUSED as keys after zlin2
#define WS_WL    9593344u    // w_z lo bf16 (131072 f); REUSED as mlist after zlin2
#define WS_WQB   9724416u    // w_q bf16 (131072 f)
#define WS_RMAX  9855488u    // rowmax ordered-uint 16384
#define WS_CNTG  9871872u    // per-row candidate count 16384
#define WS_MASK  9888256u    // per-row split overflow mask 16384
#define WS_CANDG 9904640u    // cand u32 16384*GCAP
#define WS_KEYS  WS_WH       // u64 keys 16384 (32768 f) — no init needed
#define WS_MLIST WS_WL       // mlist cnt (1 u32) + entries (8192 u32)

__device__ __forceinline__ unsigned short f2bf(float x) {
  __hip_bfloat16 h = __float2bfloat16(x);
  unsigned short u; __builtin_memcpy(&u, &h, 2); return u;
}
__device__ __forceinline__ float bf2f(unsigned short u) {
  return __uint_as_float(((unsigned)u) << 16);
}
__device__ __forceinline__ void gload_lds16(const void* g, void* l) {
  __builtin_amdgcn_global_load_lds(
      (const __attribute__((address_space(1))) unsigned int*)g,
      (__attribute__((address_space(3))) unsigned int*)l, 16, 0, 0);
}
__device__ __forceinline__ unsigned long long pack_key(float e, int code) {
  unsigned ue = __float_as_uint(e);
  ue = (ue & 0x80000000u) ? ~ue : (ue | 0x80000000u);
  return ((unsigned long long)ue << 32) | (unsigned)code;
}
__device__ __forceinline__ float ord2f(unsigned ou) {
  return (ou == 0u) ? -3.0e38f
       : ((ou & 0x80000000u) ? __uint_as_float(ou & 0x7FFFFFFFu)
                             : __uint_as_float(~ou));
}

// ---------------- Kernel 1: normalize codebook rows (+ bf16 copy) ----------------
__global__ __launch_bounds__(64) void k_codenorm(const float* __restrict__ cb,
                                                 float* __restrict__ cn,
                                                 float* __restrict__ c2,
                                                 unsigned short* __restrict__ cbf) {
  int row = blockIdx.x;
  int lane = threadIdx.x;
  float4 v = reinterpret_cast<const float4*>(cb)[row*(DC/4) + lane];
  float s = v.x*v.x + v.y*v.y + v.z*v.z + v.w*v.w;
  #pragma unroll
  for (int m = 1; m < 64; m <<= 1) s += __shfl_xor(s, m);
  float inv = 1.0f / fmaxf(sqrtf(s), 1e-12f);
  float4 o = make_float4(v.x*inv, v.y*inv, v.z*inv, v.w*inv);
  reinterpret_cast<float4*>(cn)[row*(DC/4) + lane] = o;
  ushort4 pk;
  pk.x = f2bf(o.x); pk.y = f2bf(o.y); pk.z = f2bf(o.z); pk.w = f2bf(o.w);
  reinterpret_cast<ushort4*>(cbf)[row*(DC/4) + lane] = pk;
  float s2 = o.x*o.x + o.y*o.y + o.z*o.z + o.w*o.w;
  #pragma unroll
  for (int m = 1; m < 64; m <<= 1) s2 += __shfl_xor(s2, m);
  if (lane == 0) c2[row] = s2;
}

// ---------------- Kernel 1b: weight prep ----------------
__global__ __launch_bounds__(256) void k_wprep(const float* __restrict__ wz,
                                               const float* __restrict__ wq,
                                               unsigned short* __restrict__ wh,
                                               unsigned short* __restrict__ wl,
                                               unsigned short* __restrict__ wqb) {
  int i = blockIdx.x*256 + threadIdx.x;
  float w = wz[i];
  unsigned short h = f2bf(w);
  wh[i] = h;
  wl[i] = f2bf(w - bf2f(h));
  wqb[i] = f2bf(wq[i]);
}

// ---------------- Kernel 2: z_norm = normalize(z @ w_z^T) fused, via bf16x4 MFMA -
__global__ __launch_bounds__(512, 2) void k_zlin2(const float* __restrict__ z,
                                                  const unsigned short* __restrict__ wh,
                                                  const unsigned short* __restrict__ wl,
                                                  float* __restrict__ zlin,
                                                  unsigned short* __restrict__ zbf) {
  __shared__ float As[64*64];
  __shared__ unsigned short WHs[256*64];
  __shared__ unsigned short WLs[256*64];
  const int tid = threadIdx.x;
  const int lane = tid & 63;
  const int wv = tid >> 6;
  const int wc = wv & 3;
  const int wr = wv >> 2;
  const int lo = lane & 15, hi = lane >> 4;
  const int rb = blockIdx.x * 64;

  f32x4 acc[2][4];
  #pragma unroll
  for (int m = 0; m < 2; m++)
    #pragma unroll
    for (int cs = 0; cs < 4; cs++) acc[m][cs] = (f32x4){0.f,0.f,0.f,0.f};

  int rowA[2], chA[2];
  #pragma unroll
  for (int i = 0; i < 2; i++) {
    int w = wv*2 + i;
    rowA[i] = w*4 + (lane >> 4);
    chA[i]  = (lane & 15) ^ (rowA[i] & 15);
  }
  int colW[4], chW[4];
  #pragma unroll
  for (int i = 0; i < 4; i++) {
    int w = wv*4 + i;
    colW[i] = w*8 + (lane >> 3);
    chW[i]  = (lane & 7) ^ (colW[i] & 7);
  }

  for (int kb = 0; kb < DIN; kb += 64) {
    __syncthreads();
    #pragma unroll
    for (int i = 0; i < 2; i++) {
      const char* src = (const char*)z + ((size_t)(rb + rowA[i])*DIN + kb)*4 + chA[i]*16;
      gload_lds16(src, (char*)As + (wv*2 + i)*1024);
    }
    #pragma unroll
    for (int i = 0; i < 4; i++) {
      size_t rowoff = ((size_t)colW[i]*DIN + kb)*2;
      gload_lds16((const char*)wh + rowoff + chW[i]*16, (char*)WHs + (wv*4 + i)*1024);
      gload_lds16((const char*)wl + rowoff + chW[i]*16, (char*)WLs + (wv*4 + i)*1024);
    }
    asm volatile("s_waitcnt vmcnt(0)" ::: "memory");
    __syncthreads();

    bf16x8 Bh[4][2], Bl[4][2];
    #pragma unroll
    for (int cs = 0; cs < 4; cs++)
      #pragma unroll
      for (int ks = 0; ks < 2; ks++) {
        int col = wc*64 + cs*16 + lo;
        int chl = (ks*4 + hi) ^ (lo & 7);
        Bh[cs][ks] = *reinterpret_cast<const bf16x8*>(&WHs[col*64 + chl*8]);
        Bl[cs][ks] = *reinterpret_cast<const bf16x8*>(&WLs[col*64 + chl*8]);
      }
    #pragma unroll
    for (int m = 0; m < 2; m++) {
      #pragma unroll
      for (int ks = 0; ks < 2; ks++) {
        int row = wr*32 + m*16 + lo;
        int c0 = ks*8 + hi*2;
        float4 v0 = *reinterpret_cast<const float4*>(&As[row*64 + ((c0  )^lo)*4]);
        float4 v1 = *reinterpret_cast<const float4*>(&As[row*64 + ((c0+1)^lo)*4]);
        float f[8] = {v0.x,v0.y,v0.z,v0.w,v1.x,v1.y,v1.z,v1.w};
        bf16x8 ah, al;
        #pragma unroll
        for (int e = 0; e < 8; e++) {
          unsigned short he = f2bf(f[e]);
          ah[e] = (short)he;
          al[e] = (short)f2bf(f[e] - bf2f(he));
        }
        #pragma unroll
        for (int cs = 0; cs < 4; cs++) {
          acc[m][cs] = __builtin_amdgcn_mfma_f32_16x16x32_bf16(ah, Bh[cs][ks], acc[m][cs], 0,0,0);
          acc[m][cs] = __builtin_amdgcn_mfma_f32_16x16x32_bf16(ah, Bl[cs][ks], acc[m][cs], 0,0,0);
          acc[m][cs] = __builtin_amdgcn_mfma_f32_16x16x32_bf16(al, Bh[cs][ks], acc[m][cs], 0,0,0);
          acc[m][cs] = __builtin_amdgcn_mfma_f32_16x16x32_bf16(al, Bl[cs][ks], acc[m][cs], 0,0,0);
        }
      }
    }
  }

  // ---- fused row l2norm epilogue (reuses As as 1KB reduction scratch) ----
  __syncthreads();
  float* sred = (float*)As;        // [64 rows][4 col-waves]
  float ss[2][4];
  #pragma unroll
  for (int m = 0; m < 2; m++)
    #pragma unroll
    for (int r = 0; r < 4; r++) {
      float s = 0.f;
      #pragma unroll
      for (int cs = 0; cs < 4; cs++) { float v = acc[m][cs][r]; s += v*v; }
      s += __shfl_xor(s, 1); s += __shfl_xor(s, 2);
      s += __shfl_xor(s, 4); s += __shfl_xor(s, 8);
      ss[m][r] = s;
    }
  if (lo == 0) {
    #pragma unroll
    for (int m = 0; m < 2; m++)
      #pragma unroll
      for (int r = 0; r < 4; r++) {
        int rl = wr*32 + m*16 + hi*4 + r;
        sred[rl*4 + wc] = ss[m][r];
      }
  }
  __syncthreads();
  #pragma unroll
  for (int m = 0; m < 2; m++)
    #pragma unroll
    for (int r = 0; r < 4; r++) {
      int rl = wr*32 + m*16 + hi*4 + r;
      float tot = (sred[rl*4+0] + sred[rl*4+1]) + (sred[rl*4+2] + sred[rl*4+3]);
      float inv = 1.0f / fmaxf(sqrtf(tot), 1e-12f);
      #pragma unroll
      for (int cs = 0; cs < 4; cs++) {
        float val = acc[m][cs][r] * inv;
        size_t idx = (size_t)(rb + rl)*DC + wc*64 + cs*16 + lo;
        zlin[idx] = val;
        zbf[idx]  = f2bf(val);
      }
    }
}

// ---------------- Kernel 3: SINGLE-PASS MFMA distance, cs-outer top-3 -----------
// 8 waves x 64 rows = 512 rows/block; 4x32KB buffers, group-of-2 pipeline;
// grid 256: split = bid&7 (XCD-local), rowblk = bid>>3.
// NEW: per-(cs,s) pre-filter — m4 = max(acc[s][0..3]) vs running val3min[s]
// (min over r of val3). m4 <= val3min => all 4 per-r compares provably false
// => skip. Cuts steady-state tracker VALU ~4x (the 50% VALUBusy suspect).
__global__ __launch_bounds__(512) __attribute__((amdgpu_waves_per_eu(2, 2)))
void k_dist1(
    const unsigned short* __restrict__ zbf, const unsigned short* __restrict__ cbf,
    unsigned* __restrict__ rmax_g, unsigned* __restrict__ cnt_g,
    unsigned* __restrict__ cand_g, unsigned* __restrict__ mask_g) {
  __shared__ unsigned short Bs[4][64*256];   // 128 KB staging
  const int tid  = threadIdx.x;
  const int lane = tid & 63;
  const int wv   = tid >> 6;                 // 0..7
  const int lo   = lane & 15, hi = lane >> 4;
  const int bid  = blockIdx.x;
  const int split  = bid & 7;
  const int rowblk = bid >> 3;
  const int rbw  = rowblk * 512 + wv * 64;
  const int cb0  = split * SPLITK;

  bf16x8 a[4][8];
  #pragma unroll
  for (int s = 0; s < 4; s++)
    #pragma unroll
    for (int ks = 0; ks < 8; ks++)
      a[s][ks] = *reinterpret_cast<const bf16x8*>(
          &zbf[(size_t)(rbw + s*16 + lo)*DC + ks*32 + hi*8]);
  #pragma unroll
  for (int s = 0; s < 4; s++)
    #pragma unroll
    for (int ks = 0; ks < 8; ks++)
      asm volatile("" : "+v"(a[s][ks]));

  float val1[4][4], val2[4][4], val3[4][4], val3min[4];
  unsigned meta_p[8];    // slot=s*4+r; reg=slot>>1, sh=(slot&1)*16; m1|m2<<8
  #pragma unroll
  for (int s = 0; s < 4; s++) {
    #pragma unroll
    for (int r = 0; r < 4; r++) {
      val1[s][r] = -3.0e38f; val2[s][r] = -3.0e38f; val3[s][r] = -3.0e38f;
    }
    val3min[s] = -3.0e38f;
  }
  #pragma unroll
  for (int i = 0; i < 8; i++) meta_p[i] = 0;

  int soff[4];
  #pragma unroll
  for (int i = 0; i < 4; i++) {
    int code = (wv*4 + i)*2 + (lane >> 5);
    int chg  = (lane & 31) ^ (code & 7);
    soff[i]  = code*512 + chg*16;
  }
  const char* cb_base = (const char*)cbf + (size_t)cb0*512;

#define STAGE(T,B) { _Pragma("unroll") \
    for (int i = 0; i < 4; i++) \
      gload_lds16(cb_base + (size_t)(T)*32768 + soff[i], \
                  (char*)&Bs[B][0] + (wv*4 + i)*1024); }

  STAGE(0,0); STAGE(1,1);
  for (int g = 0; g < NG; g++) {
    asm volatile("s_waitcnt vmcnt(0)" ::: "memory");
    __builtin_amdgcn_s_barrier();
    asm volatile("" ::: "memory");
    if (g + 1 < NG) { STAGE(2*(g+1), ((g+1)&1)*2); STAGE(2*(g+1)+1, ((g+1)&1)*2+1); }
    #pragma unroll
    for (int u = 0; u < 2; u++) {
      const int t = 2*g + u;
      const unsigned short* Bp = &Bs[(g&1)*2 + u][0];
      // cs-column outer: only 4 f32x4 accumulators live at a time
      #pragma unroll
      for (int cs = 0; cs < 4; cs++) {
        f32x4 acc[4];
        #pragma unroll
        for (int s = 0; s < 4; s++) acc[s] = (f32x4){0.f,0.f,0.f,0.f};
        #pragma unroll
        for (int ks = 0; ks < 8; ks++) {
          const int chl = (ks*4 + hi) ^ (lo & 7);
          bf16x8 b = *reinterpret_cast<const bf16x8*>(&Bp[(cs*16 + lo)*256 + chl*8]);
          #pragma unroll
          for (int s = 0; s < 4; s++)
            acc[s] = __builtin_amdgcn_mfma_f32_16x16x32_bf16(a[s][ks], b, acc[s], 0,0,0);
        }
        const unsigned mc = (unsigned)(t*4 + cs);
        #pragma unroll
        for (int s = 0; s < 4; s++) {
          // pre-filter: if max over r <= min over r of val3, no update possible
          float m4 = fmaxf(fmaxf(acc[s][0], acc[s][1]),
                           fmaxf(acc[s][2], acc[s][3]));
          if (m4 > val3min[s]) {
            #pragma unroll
            for (int r = 0; r < 4; r++) {
              float v = acc[s][r];
              if (v > val3[s][r]) {
                const int reg = (s*4 + r) >> 1, sh = ((s*4 + r) & 1)*16;
                unsigned m = (meta_p[reg] >> sh) & 0xFFFFu;
                if (v > val1[s][r]) {
                  val3[s][r] = val2[s][r]; val2[s][r] = val1[s][r]; val1[s][r] = v;
                  m = ((m & 0xFFu) << 8) | mc;
                } else if (v > val2[s][r]) {
                  val3[s][r] = val2[s][r]; val2[s][r] = v;
                  m = (m & 0xFFu) | (mc << 8);
                } else {
                  val3[s][r] = v;
                }
                meta_p[reg] = (meta_p[reg] & ~(0xFFFFu << sh)) | (m << sh);
              }
            }
            val3min[s] = fminf(fminf(val3[s][0], val3[s][1]),
                               fminf(val3[s][2], val3[s][3]));
          }
        }
      }
    }
  }

  // ====== end: reduce -> thr, publish, emit top-1 & top-2, mask val3 hits ======
  #pragma unroll
  for (int s = 0; s < 4; s++)
    #pragma unroll
    for (int r = 0; r < 4; r++) {
      const int reg = (s*4 + r) >> 1, sh = ((s*4 + r) & 1)*16;
      float nm = val1[s][r];
      nm = fmaxf(nm, __shfl_xor(nm, 1));
      nm = fmaxf(nm, __shfl_xor(nm, 2));
      nm = fmaxf(nm, __shfl_xor(nm, 4));
      nm = fmaxf(nm, __shfl_xor(nm, 8));
      const float thr = nm - MARGIN;
      const int row = rbw + s*16 + hi*4 + r;
      if (lo == 0) {
        unsigned b = __float_as_uint(nm);
        unsigned ou = (b & 0x80000000u) ? ~b : (b | 0x80000000u);
        atomicMax(&rmax_g[row], ou);
      }
      unsigned m = (meta_p[reg] >> sh) & 0xFFFFu;
      if (val1[s][r] >= thr) {
        unsigned m1 = m & 0xFFu;
        int code = cb0 + (int)(m1 >> 2)*64 + (int)(m1 & 3)*16 + lo;
        unsigned ent = ((unsigned)f2bf(val1[s][r]) << 16) | (unsigned)code;
        unsigned g = atomicAdd(&cnt_g[row], 1u);
        if (g < GCAP) cand_g[(size_t)row*GCAP + g] = ent;
        else atomicOr(&mask_g[row], 1u << split);
      }
      if (val2[s][r] >= thr) {
        unsigned m2 = (m >> 8) & 0xFFu;
        int code = cb0 + (int)(m2 >> 2)*64 + (int)(m2 & 3)*16 + lo;
        unsigned ent = ((unsigned)f2bf(val2[s][r]) << 16) | (unsigned)code;
        unsigned g = atomicAdd(&cnt_g[row], 1u);
        if (g < GCAP) cand_g[(size_t)row*GCAP + g] = ent;
        else atomicOr(&mask_g[row], 1u << split);
      }
      if (val3[s][r] >= thr) atomicOr(&mask_g[row], 1u << split);
    }
#undef STAGE
}

// ---------------- Kernel 3b: per-row candidate refine; emit mask work list ------
__global__ __launch_bounds__(256) void k_refine(
    const float* __restrict__ zn, const float* __restrict__ cn,
    const float* __restrict__ c2,
    const unsigned* __restrict__ rmax_g, const unsigned* __restrict__ cnt_g,
    const unsigned* __restrict__ cand_g, const unsigned* __restrict__ mask_g,
    unsigned long long* __restrict__ keys,
    unsigned* __restrict__ mlc, unsigned* __restrict__ mlist) {
  const int wv = threadIdx.x >> 6;
  const int lane = threadIdx.x & 63;
  const int row = blockIdx.x*4 + wv;

  float4 zv = *reinterpret_cast<const float4*>(&zn[(size_t)row*DC + lane*4]);

  float rmx = ord2f(rmax_g[row]);
  float thr = rmx - PRUNE;

  unsigned ntot = cnt_g[row];
  unsigned nc = ntot > GCAP ? GCAP : ntot;

  unsigned ent = (lane < (int)nc) ? cand_g[(size_t)row*GCAP + lane] : 0u;
  bool keep = (lane < (int)nc) && (bf2f((unsigned short)(ent >> 16)) >= thr);
  unsigned long long ball = __ballot(keep);

  unsigned long long bk = ~0ull;
  while (ball) {
    int j = __ffsll((long long)ball) - 1;
    ball &= ball - 1;
    int code = (int)(__shfl(ent, j) & 0xFFFFu);
    float4 yv = *reinterpret_cast<const float4*>(&cn[(size_t)code*DC + lane*4]);
    float p = zv.x*yv.x + zv.y*yv.y + zv.z*yv.z + zv.w*yv.w;
    #pragma unroll
    for (int m = 1; m < 64; m <<= 1) p += __shfl_xor(p, m);
    unsigned long long key = pack_key(c2[code] - 2.f*p, code);
    bk = key < bk ? key : bk;
  }

  unsigned msk = mask_g[row];
  if (msk) {
    if (lane == 0) {
      unsigned mm = msk;
      while (mm) {
        int s = __ffs(mm) - 1;
        mm &= mm - 1;
        unsigned idx = atomicAdd(mlc, 1u);
        if (idx < MLMAX) mlist[1 + idx] = ((unsigned)row << 3) | (unsigned)s;
        else msk |= 0x80000000u;
      }
    }
    msk = __shfl(msk, 0);
    if (msk & 0x80000000u) {
      for (int s = 0; s < DSPLIT; s++) if (msk & (1u << s)) {
        for (int k = 0; k < SPLITK; k += 4) {
          #pragma unroll
          for (int j = 0; j < 4; j++) {
            int code = s*SPLITK + k + j;
            float4 yv = *reinterpret_cast<const float4*>(&cn[(size_t)code*DC + lane*4]);
            float p = zv.x*yv.x + zv.y*yv.y + zv.z*yv.z + zv.w*yv.w;
            #pragma unroll
            for (int m = 1; m < 64; m <<= 1) p += __shfl_xor(p, m);
            unsigned long long key = pack_key(c2[code] - 2.f*p, code);
            bk = key < bk ? key : bk;
          }
        }
      }
    }
  }

  #pragma unroll
  for (int m = 1; m < 64; m <<= 1) {
    unsigned long long o = __shfl_xor(bk, m);
    bk = o < bk ? o : bk;
  }
  if (lane == 0) keys[row] = bk;
}

// ---------------- Kernel 3c: distributed mask scan (64-code chunks/wave) --------
__global__ __launch_bounds__(256) void k_maskscan(
    const float* __restrict__ zn, const float* __restrict__ cn,
    const float* __restrict__ c2,
    const unsigned* __restrict__ mlist,
    unsigned long long* __restrict__ keys) {
  unsigned n = mlist[0]; if (n > MLMAX) n = MLMAX;
  const unsigned total = n * 16;
  const unsigned nw = gridDim.x * 4;
  const unsigned gw = blockIdx.x*4 + (threadIdx.x >> 6);
  const int lane = threadIdx.x & 63;
  for (unsigned w = gw; w < total; w += nw) {
    unsigned ent = mlist[1 + (w >> 4)];
    int chunk = (int)(w & 15);
    int row = (int)(ent >> 3);
    int c0 = (int)(ent & 7)*SPLITK + chunk*64;
    float4 zv = *reinterpret_cast<const float4*>(&zn[(size_t)row*DC + lane*4]);
    unsigned long long bk = ~0ull;
    for (int k = 0; k < 64; k += 4) {
      #pragma unroll
      for (int j = 0; j < 4; j++) {
        int code = c0 + k + j;
        float4 yv = *reinterpret_cast<const float4*>(&cn[(size_t)code*DC + lane*4]);
        float p = zv.x*yv.x + zv.y*yv.y + zv.z*yv.z + zv.w*yv.w;
        #pragma unroll
        for (int m = 1; m < 64; m <<= 1) p += __shfl_xor(p, m);
        unsigned long long key = pack_key(c2[code] - 2.f*p, code);
        bk = key < bk ? key : bk;
      }
    }
    if (lane == 0) atomicMin(&keys[row], bk);
  }
}

// ---------------- Kernel 3d: keys -> codes ----------------
__global__ __launch_bounds__(256) void k_final(const unsigned long long* __restrict__ keys,
                                               int* __restrict__ ci,
                                               float* __restrict__ cf) {
  int r = blockIdx.x*256 + threadIdx.x;
  int idx = (int)(keys[r] & 0xFFFFFFFFull);
  ci[r] = idx;
  cf[r] = (float)idx;
}

// ---------------- Kernel 4: q = gather(cbf) @ wqb^T via MFMA ----------------
__global__ __launch_bounds__(256, 2) void k_qgemm2(const int* __restrict__ ci,
                                                   const unsigned short* __restrict__ cbf,
                                                   const unsigned short* __restrict__ wqb,
                                                   float* __restrict__ qout) {
  __shared__ unsigned short Bs[64*256];
  const int tid  = threadIdx.x;
  const int lane = tid & 63;
  const int wv   = tid >> 6;
  const int lo   = lane & 15, hi = lane >> 4;
  const int rbw  = blockIdx.x * 256 + wv * 64;
  const int db   = blockIdx.y * 128;

  bf16x8 a[4][8];
  #pragma unroll
  for (int s = 0; s < 4; s++) {
    int code = ci[rbw + s*16 + lo];
    #pragma unroll
    for (int ks = 0; ks < 8; ks++)
      a[s][ks] = *reinterpret_cast<const bf16x8*>(&cbf[(size_t)code*DC + ks*32 + hi*8]);
  }
  #pragma unroll
  for (int s = 0; s < 4; s++)
    #pragma unroll
    for (int ks = 0; ks < 8; ks++)
      asm volatile("" : "+v"(a[s][ks]));

  int soff[8];
  #pragma unroll
  for (int i = 0; i < 8; i++) {
    int d = (wv*8 + i)*2 + (lane >> 5);
    int chg = (lane & 31) ^ (d & 7);
    soff[i] = d*512 + chg*16;
  }

  for (int t = 0; t < 2; t++) {
    const int dbx = db + t*64;
    __syncthreads();
    #pragma unroll
    for (int i = 0; i < 8; i++)
      gload_lds16((const char*)wqb + (size_t)dbx*512 + soff[i], (char*)Bs + (wv*8 + i)*1024);
    asm volatile("s_waitcnt vmcnt(0)" ::: "memory");
    __syncthreads();

    f32x4 acc[4][4];
    #pragma unroll
    for (int s = 0; s < 4; s++)
      #pragma unroll
      for (int cs = 0; cs < 4; cs++) acc[s][cs] = (f32x4){0.f,0.f,0.f,0.f};
    #pragma unroll
    for (int ks = 0; ks < 8; ks++) {
      const int chl = (ks*4 + hi) ^ (lo & 7);
      #pragma unroll
      for (int cs = 0; cs < 4; cs++) {
        bf16x8 b = *reinterpret_cast<const bf16x8*>(&Bs[(cs*16 + lo)*256 + chl*8]);
        #pragma unroll
        for (int s = 0; s < 4; s++)
          acc[s][cs] = __builtin_amdgcn_mfma_f32_16x16x32_bf16(a[s][ks], b, acc[s][cs], 0,0,0);
      }
    }
    #pragma unroll
    for (int s = 0; s < 4; s++)
      #pragma unroll
      for (int cs = 0; cs < 4; cs++)
        #pragma unroll
        for (int r = 0; r < 4; r++)
          qout[(size_t)(rbw + s*16 + hi*4 + r)*DIN + dbx + cs*16 + lo] = acc[s][cs][r];
  }
}

// ---------------- Kernel 5/6: quantize loss ----------------
__global__ __launch_bounds__(256) void k_losspart(const float* __restrict__ zn,
                                                  const float* __restrict__ cn,
                                                  const int* __restrict__ codes_i,
                                                  float* __restrict__ part) {
  const int tid = threadIdx.x;
  const size_t base = (size_t)blockIdx.x * 8192;
  float s = 0.f;
  #pragma unroll
  for (int k = 0; k < 32; k++) {
    size_t e = base + (size_t)k*256 + tid;
    int r = (int)(e >> 8);
    int c = (int)(e & 255);
    float d = cn[(size_t)codes_i[r]*DC + c] - zn[e];
    s += d * d;
  }
  #pragma unroll
  for (int m = 1; m < 64; m <<= 1) s += __shfl_xor(s, m);
  __shared__ float red[4];
  if ((tid & 63) == 0) red[tid >> 6] = s;
  __syncthreads();
  if (tid == 0) part[blockIdx.x] = (red[0] + red[1]) + (red[2] + red[3]);
}

__global__ __launch_bounds__(256) void k_lossfinal(const float* __restrict__ part,
                                                   float* __restrict__ loss_out) {
  const int tid = threadIdx.x;
  float s = part[tid] + part[tid + 256];
  #pragma unroll
  for (int m = 1; m < 64; m <<= 1) s += __shfl_xor(s, m);
  __shared__ float red[4];
  if ((tid & 63) == 0) red[tid >> 6] = s;
  __syncthreads();
  if (tid == 0) {
    float tot = (red[0] + red[1]) + (red[2] + red[3]);
    loss_out[0] = tot * 1.25f / 4194304.0f;
  }
}

extern "C" void kernel_launch(void* const* d_in, const int* in_sizes, int n_in,
                              void* d_out, int out_size, void* d_ws, size_t ws_size,
                              hipStream_t stream) {
  const float* z  = (const float*)d_in[0];
  const float* cb = (const float*)d_in[1];
  const float* wz = (const float*)d_in[2];
  const float* wq = (const float*)d_in[3];

  float* out = (float*)d_out;
  float* q_out   = out;
  float* codes_f = out + (size_t)R_TOT*DIN;
  float* loss_o  = codes_f + R_TOT;

  float* ws = (float*)d_ws;
  float* cn = ws + WS_CN;
  float* zn = ws + WS_ZN;
  float* c2 = ws + WS_C2;
  int*   ci = (int*)(ws + WS_CODES);
  float* pt = ws + WS_PART;
  unsigned short* cbf = (unsigned short*)(ws + WS_CBF);
  unsigned short* zbf = (unsigned short*)(ws + WS_ZBF);
  unsigned short* wh  = (unsigned short*)(ws + WS_WH);
  unsigned short* wl  = (unsigned short*)(ws + WS_WL);
  unsigned short* wqb = (unsigned short*)(ws + WS_WQB);
  unsigned* rmax = (unsigned*)(ws + WS_RMAX);
  unsigned* cntg = (unsigned*)(ws + WS_CNTG);
  unsigned* maskg = (unsigned*)(ws + WS_MASK);
  unsigned* candg = (unsigned*)(ws + WS_CANDG);
  unsigned long long* keys = (unsigned long long*)(ws + WS_KEYS);   // reuses WH
  unsigned* mlist = (unsigned*)(ws + WS_MLIST);                     // reuses WL

  // rmax, cntg, mask are contiguous: one memset
  hipMemsetAsync(rmax, 0, (size_t)3*R_TOT*sizeof(unsigned), stream);
  hipLaunchKernelGGL(k_codenorm, dim3(KCB), dim3(64), 0, stream, cb, cn, c2, cbf);
  hipLaunchKernelGGL(k_wprep, dim3(1024), dim3(256), 0, stream, wz, wq, wh, wl, wqb);
  hipLaunchKernelGGL(k_zlin2, dim3(R_TOT/64), dim3(512), 0, stream, z, wh, wl, zn, zbf);
  // wh/wl regions are dead after k_zlin2 -> reuse as keys/mlist
  hipMemsetAsync(mlist, 0, sizeof(unsigned), stream);
  hipLaunchKernelGGL(k_dist1, dim3((R_TOT/512)*DSPLIT), dim3(512), 0, stream,
                     zbf, cbf, rmax, cntg, candg, maskg);
  hipLaunchKernelGGL(k_refine, dim3(R_TOT/4), dim3(256), 0, stream,
                     zn, cn, c2, rmax, cntg, candg, maskg, keys, mlist, mlist);
  hipLaunchKernelGGL(k_maskscan, dim3(512), dim3(256), 0, stream,
                     zn, cn, c2, mlist, keys);
  hipLaunchKernelGGL(k_final, dim3(R_TOT/256), dim3(256), 0, stream, keys, ci, codes_f);
  hipLaunchKernelGGL(k_qgemm2, dim3(R_TOT/256, DIN/128), dim3(256), 0, stream, ci, cbf, wqb, q_out);
  hipLaunchKernelGGL(k_losspart, dim3(512), dim3(256), 0, stream, zn, cn, ci, pt);
  hipLaunchKernelGGL(k_lossfinal, dim3(1), dim3(256), 0, stream, pt, loss_o);
}

// Round 28
// 274.396 us; speedup vs baseline: 1.0337x; 1.0337x over previous
//
#include <hip/hip_runtime.h>
#include <hip/hip_bf16.h>
#include <math.h>

#define R_TOT 16384   // B*T
#define DIN   1024    // D
#define DC    256     // Dc
#define KCB   8192    // K codebook entries
#define DSPLIT 8
#define SPLITK (KCB/DSPLIT)   // 1024 codes per split
#define NT (SPLITK/64)        // 16 tiles of 64 codes
#define NG (NT/2)             // 8 groups of 2 tiles
#define MARGIN 0.0085f        // hard bound 2*delta_bf16 = 0.0079; +slack
#define PRUNE  0.0105f        // 0.0079 + bf16 value-store err 0.002 + slack
#define GCAP 64
#define MLMAX 8192

typedef __attribute__((ext_vector_type(8))) short bf16x8;
typedef __attribute__((ext_vector_type(4))) float f32x4;

// ws layout (float offsets)
#define WS_CN    0u          // code_norm f32 8192*256
#define WS_ZN    2097152u    // z_norm f32 16384*256
#define WS_C2    6291456u    // |c|^2 8192
#define WS_CODES 6299648u    // codes int 16384
#define WS_PART  6316032u    // loss partials 512
#define WS_CBF   6316544u    // code_norm bf16 (1048576 f)
#define WS_ZBF   7365120u    // z_norm bf16 (2097152 f)
#define WS_WH    9462272u    // w_z hi bf16 (131072 f); REUSED as keys after zlin2
#define WS_WL    9593344u    // w_z lo bf16 (131072 f); REUSED as mlist after zlin2
#define WS_WQB   9724416u    // w_q bf16 (131072 f)
#define WS_RMAX  9855488u    // rowmax ordered-uint 16384
#define WS_CNTG  9871872u    // per-row candidate count 16384
#define WS_MASK  9888256u    // per-row split overflow mask 16384
#define WS_CANDG 9904640u    // cand u32 16384*GCAP
#define WS_KEYS  WS_WH       // u64 keys 16384 (32768 f) — no init needed
#define WS_MLIST WS_WL       // mlist cnt (1 u32) + entries (8192 u32)

__device__ __forceinline__ unsigned short f2bf(float x) {
  __hip_bfloat16 h = __float2bfloat16(x);
  unsigned short u; __builtin_memcpy(&u, &h, 2); return u;
}
__device__ __forceinline__ float bf2f(unsigned short u) {
  return __uint_as_float(((unsigned)u) << 16);
}
__device__ __forceinline__ void gload_lds16(const void* g, void* l) {
  __builtin_amdgcn_global_load_lds(
      (const __attribute__((address_space(1))) unsigned int*)g,
      (__attribute__((address_space(3))) unsigned int*)l, 16, 0, 0);
}
__device__ __forceinline__ unsigned long long pack_key(float e, int code) {
  unsigned ue = __float_as_uint(e);
  ue = (ue & 0x80000000u) ? ~ue : (ue | 0x80000000u);
  return ((unsigned long long)ue << 32) | (unsigned)code;
}
__device__ __forceinline__ float ord2f(unsigned ou) {
  return (ou == 0u) ? -3.0e38f
       : ((ou & 0x80000000u) ? __uint_as_float(ou & 0x7FFFFFFFu)
                             : __uint_as_float(~ou));
}

// ---------------- Kernel 1: normalize codebook rows (+ bf16 copy) ----------------
__global__ __launch_bounds__(64) void k_codenorm(const float* __restrict__ cb,
                                                 float* __restrict__ cn,
                                                 float* __restrict__ c2,
                                                 unsigned short* __restrict__ cbf) {
  int row = blockIdx.x;
  int lane = threadIdx.x;
  float4 v = reinterpret_cast<const float4*>(cb)[row*(DC/4) + lane];
  float s = v.x*v.x + v.y*v.y + v.z*v.z + v.w*v.w;
  #pragma unroll
  for (int m = 1; m < 64; m <<= 1) s += __shfl_xor(s, m);
  float inv = 1.0f / fmaxf(sqrtf(s), 1e-12f);
  float4 o = make_float4(v.x*inv, v.y*inv, v.z*inv, v.w*inv);
  reinterpret_cast<float4*>(cn)[row*(DC/4) + lane] = o;
  ushort4 pk;
  pk.x = f2bf(o.x); pk.y = f2bf(o.y); pk.z = f2bf(o.z); pk.w = f2bf(o.w);
  reinterpret_cast<ushort4*>(cbf)[row*(DC/4) + lane] = pk;
  float s2 = o.x*o.x + o.y*o.y + o.z*o.z + o.w*o.w;
  #pragma unroll
  for (int m = 1; m < 64; m <<= 1) s2 += __shfl_xor(s2, m);
  if (lane == 0) c2[row] = s2;
}

// ---------------- Kernel 1b: weight prep ----------------
__global__ __launch_bounds__(256) void k_wprep(const float* __restrict__ wz,
                                               const float* __restrict__ wq,
                                               unsigned short* __restrict__ wh,
                                               unsigned short* __restrict__ wl,
                                               unsigned short* __restrict__ wqb) {
  int i = blockIdx.x*256 + threadIdx.x;
  float w = wz[i];
  unsigned short h = f2bf(w);
  wh[i] = h;
  wl[i] = f2bf(w - bf2f(h));
  wqb[i] = f2bf(wq[i]);
}

// ---------------- Kernel 2: z_norm = normalize(z @ w_z^T) fused, via bf16x4 MFMA -
// Epilogue computes the row l2norm in-block; reuses As as 1KB reduction scratch;
// writes normalized zn (f32) and zbf (bf16) directly (k_norm pass eliminated).
__global__ __launch_bounds__(512, 2) void k_zlin2(const float* __restrict__ z,
                                                  const unsigned short* __restrict__ wh,
                                                  const unsigned short* __restrict__ wl,
                                                  float* __restrict__ zlin,
                                                  unsigned short* __restrict__ zbf) {
  __shared__ float As[64*64];
  __shared__ unsigned short WHs[256*64];
  __shared__ unsigned short WLs[256*64];
  const int tid = threadIdx.x;
  const int lane = tid & 63;
  const int wv = tid >> 6;
  const int wc = wv & 3;
  const int wr = wv >> 2;
  const int lo = lane & 15, hi = lane >> 4;
  const int rb = blockIdx.x * 64;

  f32x4 acc[2][4];
  #pragma unroll
  for (int m = 0; m < 2; m++)
    #pragma unroll
    for (int cs = 0; cs < 4; cs++) acc[m][cs] = (f32x4){0.f,0.f,0.f,0.f};

  int rowA[2], chA[2];
  #pragma unroll
  for (int i = 0; i < 2; i++) {
    int w = wv*2 + i;
    rowA[i] = w*4 + (lane >> 4);
    chA[i]  = (lane & 15) ^ (rowA[i] & 15);
  }
  int colW[4], chW[4];
  #pragma unroll
  for (int i = 0; i < 4; i++) {
    int w = wv*4 + i;
    colW[i] = w*8 + (lane >> 3);
    chW[i]  = (lane & 7) ^ (colW[i] & 7);
  }

  for (int kb = 0; kb < DIN; kb += 64) {
    __syncthreads();
    #pragma unroll
    for (int i = 0; i < 2; i++) {
      const char* src = (const char*)z + ((size_t)(rb + rowA[i])*DIN + kb)*4 + chA[i]*16;
      gload_lds16(src, (char*)As + (wv*2 + i)*1024);
    }
    #pragma unroll
    for (int i = 0; i < 4; i++) {
      size_t rowoff = ((size_t)colW[i]*DIN + kb)*2;
      gload_lds16((const char*)wh + rowoff + chW[i]*16, (char*)WHs + (wv*4 + i)*1024);
      gload_lds16((const char*)wl + rowoff + chW[i]*16, (char*)WLs + (wv*4 + i)*1024);
    }
    asm volatile("s_waitcnt vmcnt(0)" ::: "memory");
    __syncthreads();

    bf16x8 Bh[4][2], Bl[4][2];
    #pragma unroll
    for (int cs = 0; cs < 4; cs++)
      #pragma unroll
      for (int ks = 0; ks < 2; ks++) {
        int col = wc*64 + cs*16 + lo;
        int chl = (ks*4 + hi) ^ (lo & 7);
        Bh[cs][ks] = *reinterpret_cast<const bf16x8*>(&WHs[col*64 + chl*8]);
        Bl[cs][ks] = *reinterpret_cast<const bf16x8*>(&WLs[col*64 + chl*8]);
      }
    #pragma unroll
    for (int m = 0; m < 2; m++) {
      #pragma unroll
      for (int ks = 0; ks < 2; ks++) {
        int row = wr*32 + m*16 + lo;
        int c0 = ks*8 + hi*2;
        float4 v0 = *reinterpret_cast<const float4*>(&As[row*64 + ((c0  )^lo)*4]);
        float4 v1 = *reinterpret_cast<const float4*>(&As[row*64 + ((c0+1)^lo)*4]);
        float f[8] = {v0.x,v0.y,v0.z,v0.w,v1.x,v1.y,v1.z,v1.w};
        bf16x8 ah, al;
        #pragma unroll
        for (int e = 0; e < 8; e++) {
          unsigned short he = f2bf(f[e]);
          ah[e] = (short)he;
          al[e] = (short)f2bf(f[e] - bf2f(he));
        }
        #pragma unroll
        for (int cs = 0; cs < 4; cs++) {
          acc[m][cs] = __builtin_amdgcn_mfma_f32_16x16x32_bf16(ah, Bh[cs][ks], acc[m][cs], 0,0,0);
          acc[m][cs] = __builtin_amdgcn_mfma_f32_16x16x32_bf16(ah, Bl[cs][ks], acc[m][cs], 0,0,0);
          acc[m][cs] = __builtin_amdgcn_mfma_f32_16x16x32_bf16(al, Bh[cs][ks], acc[m][cs], 0,0,0);
          acc[m][cs] = __builtin_amdgcn_mfma_f32_16x16x32_bf16(al, Bl[cs][ks], acc[m][cs], 0,0,0);
        }
      }
    }
  }

  // ---- fused row l2norm epilogue (reuses As as 1KB reduction scratch) ----
  __syncthreads();
  float* sred = (float*)As;        // [64 rows][4 col-waves]
  float ss[2][4];
  #pragma unroll
  for (int m = 0; m < 2; m++)
    #pragma unroll
    for (int r = 0; r < 4; r++) {
      float s = 0.f;
      #pragma unroll
      for (int cs = 0; cs < 4; cs++) { float v = acc[m][cs][r]; s += v*v; }
      s += __shfl_xor(s, 1); s += __shfl_xor(s, 2);
      s += __shfl_xor(s, 4); s += __shfl_xor(s, 8);
      ss[m][r] = s;
    }
  if (lo == 0) {
    #pragma unroll
    for (int m = 0; m < 2; m++)
      #pragma unroll
      for (int r = 0; r < 4; r++) {
        int rl = wr*32 + m*16 + hi*4 + r;
        sred[rl*4 + wc] = ss[m][r];
      }
  }
  __syncthreads();
  #pragma unroll
  for (int m = 0; m < 2; m++)
    #pragma unroll
    for (int r = 0; r < 4; r++) {
      int rl = wr*32 + m*16 + hi*4 + r;
      float tot = (sred[rl*4+0] + sred[rl*4+1]) + (sred[rl*4+2] + sred[rl*4+3]);
      float inv = 1.0f / fmaxf(sqrtf(tot), 1e-12f);
      #pragma unroll
      for (int cs = 0; cs < 4; cs++) {
        float val = acc[m][cs][r] * inv;
        size_t idx = (size_t)(rb + rl)*DC + wc*64 + cs*16 + lo;
        zlin[idx] = val;
        zbf[idx]  = f2bf(val);
      }
    }
}

// ---------------- Kernel 3: SINGLE-PASS MFMA distance, cs-outer top-3 -----------
// 8 waves x 64 rows = 512 rows/block; 4x32KB buffers, group-of-2 pipeline;
// grid 256: split = bid&7 (XCD-local), rowblk = bid>>3.
// Measured-best dist1 (141 us; r21/r23/r25/r26). cs-outer: acc[4] (16 VGPR)
// live; top-3 trackers plain f32; meta packed. Emit top-1 & top-2 if >= thr;
// mask only val3 >= thr -> distributed maskscan. (Pre-filter variant r27: -12us
// regression, reverted.)
__global__ __launch_bounds__(512) __attribute__((amdgpu_waves_per_eu(2, 2)))
void k_dist1(
    const unsigned short* __restrict__ zbf, const unsigned short* __restrict__ cbf,
    unsigned* __restrict__ rmax_g, unsigned* __restrict__ cnt_g,
    unsigned* __restrict__ cand_g, unsigned* __restrict__ mask_g) {
  __shared__ unsigned short Bs[4][64*256];   // 128 KB staging
  const int tid  = threadIdx.x;
  const int lane = tid & 63;
  const int wv   = tid >> 6;                 // 0..7
  const int lo   = lane & 15, hi = lane >> 4;
  const int bid  = blockIdx.x;
  const int split  = bid & 7;
  const int rowblk = bid >> 3;
  const int rbw  = rowblk * 512 + wv * 64;
  const int cb0  = split * SPLITK;

  bf16x8 a[4][8];
  #pragma unroll
  for (int s = 0; s < 4; s++)
    #pragma unroll
    for (int ks = 0; ks < 8; ks++)
      a[s][ks] = *reinterpret_cast<const bf16x8*>(
          &zbf[(size_t)(rbw + s*16 + lo)*DC + ks*32 + hi*8]);
  #pragma unroll
  for (int s = 0; s < 4; s++)
    #pragma unroll
    for (int ks = 0; ks < 8; ks++)
      asm volatile("" : "+v"(a[s][ks]));

  float val1[4][4], val2[4][4], val3[4][4];
  unsigned meta_p[8];    // slot=s*4+r; reg=slot>>1, sh=(slot&1)*16; m1|m2<<8
  #pragma unroll
  for (int s = 0; s < 4; s++)
    #pragma unroll
    for (int r = 0; r < 4; r++) {
      val1[s][r] = -3.0e38f; val2[s][r] = -3.0e38f; val3[s][r] = -3.0e38f;
    }
  #pragma unroll
  for (int i = 0; i < 8; i++) meta_p[i] = 0;

  int soff[4];
  #pragma unroll
  for (int i = 0; i < 4; i++) {
    int code = (wv*4 + i)*2 + (lane >> 5);
    int chg  = (lane & 31) ^ (code & 7);
    soff[i]  = code*512 + chg*16;
  }
  const char* cb_base = (const char*)cbf + (size_t)cb0*512;

#define STAGE(T,B) { _Pragma("unroll") \
    for (int i = 0; i < 4; i++) \
      gload_lds16(cb_base + (size_t)(T)*32768 + soff[i], \
                  (char*)&Bs[B][0] + (wv*4 + i)*1024); }

  STAGE(0,0); STAGE(1,1);
  for (int g = 0; g < NG; g++) {
    asm volatile("s_waitcnt vmcnt(0)" ::: "memory");
    __builtin_amdgcn_s_barrier();
    asm volatile("" ::: "memory");
    if (g + 1 < NG) { STAGE(2*(g+1), ((g+1)&1)*2); STAGE(2*(g+1)+1, ((g+1)&1)*2+1); }
    #pragma unroll
    for (int u = 0; u < 2; u++) {
      const int t = 2*g + u;
      const unsigned short* Bp = &Bs[(g&1)*2 + u][0];
      // cs-column outer: only 4 f32x4 accumulators live at a time
      #pragma unroll
      for (int cs = 0; cs < 4; cs++) {
        f32x4 acc[4];
        #pragma unroll
        for (int s = 0; s < 4; s++) acc[s] = (f32x4){0.f,0.f,0.f,0.f};
        #pragma unroll
        for (int ks = 0; ks < 8; ks++) {
          const int chl = (ks*4 + hi) ^ (lo & 7);
          bf16x8 b = *reinterpret_cast<const bf16x8*>(&Bp[(cs*16 + lo)*256 + chl*8]);
          #pragma unroll
          for (int s = 0; s < 4; s++)
            acc[s] = __builtin_amdgcn_mfma_f32_16x16x32_bf16(a[s][ks], b, acc[s], 0,0,0);
        }
        const unsigned mc = (unsigned)(t*4 + cs);
        #pragma unroll
        for (int s = 0; s < 4; s++)
          #pragma unroll
          for (int r = 0; r < 4; r++) {
            float v = acc[s][r];
            if (v > val3[s][r]) {
              const int reg = (s*4 + r) >> 1, sh = ((s*4 + r) & 1)*16;
              unsigned m = (meta_p[reg] >> sh) & 0xFFFFu;
              if (v > val1[s][r]) {
                val3[s][r] = val2[s][r]; val2[s][r] = val1[s][r]; val1[s][r] = v;
                m = ((m & 0xFFu) << 8) | mc;
              } else if (v > val2[s][r]) {
                val3[s][r] = val2[s][r]; val2[s][r] = v;
                m = (m & 0xFFu) | (mc << 8);
              } else {
                val3[s][r] = v;
              }
              meta_p[reg] = (meta_p[reg] & ~(0xFFFFu << sh)) | (m << sh);
            }
          }
      }
    }
  }

  // ====== end: reduce -> thr, publish, emit top-1 & top-2, mask val3 hits ======
  #pragma unroll
  for (int s = 0; s < 4; s++)
    #pragma unroll
    for (int r = 0; r < 4; r++) {
      const int reg = (s*4 + r) >> 1, sh = ((s*4 + r) & 1)*16;
      float nm = val1[s][r];
      nm = fmaxf(nm, __shfl_xor(nm, 1));
      nm = fmaxf(nm, __shfl_xor(nm, 2));
      nm = fmaxf(nm, __shfl_xor(nm, 4));
      nm = fmaxf(nm, __shfl_xor(nm, 8));
      const float thr = nm - MARGIN;
      const int row = rbw + s*16 + hi*4 + r;
      if (lo == 0) {
        unsigned b = __float_as_uint(nm);
        unsigned ou = (b & 0x80000000u) ? ~b : (b | 0x80000000u);
        atomicMax(&rmax_g[row], ou);
      }
      unsigned m = (meta_p[reg] >> sh) & 0xFFFFu;
      if (val1[s][r] >= thr) {
        unsigned m1 = m & 0xFFu;
        int code = cb0 + (int)(m1 >> 2)*64 + (int)(m1 & 3)*16 + lo;
        unsigned ent = ((unsigned)f2bf(val1[s][r]) << 16) | (unsigned)code;
        unsigned g = atomicAdd(&cnt_g[row], 1u);
        if (g < GCAP) cand_g[(size_t)row*GCAP + g] = ent;
        else atomicOr(&mask_g[row], 1u << split);
      }
      if (val2[s][r] >= thr) {
        unsigned m2 = (m >> 8) & 0xFFu;
        int code = cb0 + (int)(m2 >> 2)*64 + (int)(m2 & 3)*16 + lo;
        unsigned ent = ((unsigned)f2bf(val2[s][r]) << 16) | (unsigned)code;
        unsigned g = atomicAdd(&cnt_g[row], 1u);
        if (g < GCAP) cand_g[(size_t)row*GCAP + g] = ent;
        else atomicOr(&mask_g[row], 1u << split);
      }
      if (val3[s][r] >= thr) atomicOr(&mask_g[row], 1u << split);
    }
#undef STAGE
}

// ---------------- Kernel 3b: per-row candidate refine; emit mask work list ------
__global__ __launch_bounds__(256) void k_refine(
    const float* __restrict__ zn, const float* __restrict__ cn,
    const float* __restrict__ c2,
    const unsigned* __restrict__ rmax_g, const unsigned* __restrict__ cnt_g,
    const unsigned* __restrict__ cand_g, const unsigned* __restrict__ mask_g,
    unsigned long long* __restrict__ keys,
    unsigned* __restrict__ mlc, unsigned* __restrict__ mlist) {
  const int wv = threadIdx.x >> 6;
  const int lane = threadIdx.x & 63;
  const int row = blockIdx.x*4 + wv;

  float4 zv = *reinterpret_cast<const float4*>(&zn[(size_t)row*DC + lane*4]);

  float rmx = ord2f(rmax_g[row]);
  float thr = rmx - PRUNE;

  unsigned ntot = cnt_g[row];
  unsigned nc = ntot > GCAP ? GCAP : ntot;

  unsigned ent = (lane < (int)nc) ? cand_g[(size_t)row*GCAP + lane] : 0u;
  bool keep = (lane < (int)nc) && (bf2f((unsigned short)(ent >> 16)) >= thr);
  unsigned long long ball = __ballot(keep);

  unsigned long long bk = ~0ull;
  while (ball) {
    int j = __ffsll((long long)ball) - 1;
    ball &= ball - 1;
    int code = (int)(__shfl(ent, j) & 0xFFFFu);
    float4 yv = *reinterpret_cast<const float4*>(&cn[(size_t)code*DC + lane*4]);
    float p = zv.x*yv.x + zv.y*yv.y + zv.z*yv.z + zv.w*yv.w;
    #pragma unroll
    for (int m = 1; m < 64; m <<= 1) p += __shfl_xor(p, m);
    unsigned long long key = pack_key(c2[code] - 2.f*p, code);
    bk = key < bk ? key : bk;
  }

  unsigned msk = mask_g[row];
  if (msk) {
    if (lane == 0) {
      unsigned mm = msk;
      while (mm) {
        int s = __ffs(mm) - 1;
        mm &= mm - 1;
        unsigned idx = atomicAdd(mlc, 1u);
        if (idx < MLMAX) mlist[1 + idx] = ((unsigned)row << 3) | (unsigned)s;
        else msk |= 0x80000000u;
      }
    }
    msk = __shfl(msk, 0);
    if (msk & 0x80000000u) {
      for (int s = 0; s < DSPLIT; s++) if (msk & (1u << s)) {
        for (int k = 0; k < SPLITK; k += 4) {
          #pragma unroll
          for (int j = 0; j < 4; j++) {
            int code = s*SPLITK + k + j;
            float4 yv = *reinterpret_cast<const float4*>(&cn[(size_t)code*DC + lane*4]);
            float p = zv.x*yv.x + zv.y*yv.y + zv.z*yv.z + zv.w*yv.w;
            #pragma unroll
            for (int m = 1; m < 64; m <<= 1) p += __shfl_xor(p, m);
            unsigned long long key = pack_key(c2[code] - 2.f*p, code);
            bk = key < bk ? key : bk;
          }
        }
      }
    }
  }

  #pragma unroll
  for (int m = 1; m < 64; m <<= 1) {
    unsigned long long o = __shfl_xor(bk, m);
    bk = o < bk ? o : bk;
  }
  if (lane == 0) keys[row] = bk;
}

// ---------------- Kernel 3c: distributed mask scan (64-code chunks/wave) --------
__global__ __launch_bounds__(256) void k_maskscan(
    const float* __restrict__ zn, const float* __restrict__ cn,
    const float* __restrict__ c2,
    const unsigned* __restrict__ mlist,
    unsigned long long* __restrict__ keys) {
  unsigned n = mlist[0]; if (n > MLMAX) n = MLMAX;
  const unsigned total = n * 16;
  const unsigned nw = gridDim.x * 4;
  const unsigned gw = blockIdx.x*4 + (threadIdx.x >> 6);
  const int lane = threadIdx.x & 63;
  for (unsigned w = gw; w < total; w += nw) {
    unsigned ent = mlist[1 + (w >> 4)];
    int chunk = (int)(w & 15);
    int row = (int)(ent >> 3);
    int c0 = (int)(ent & 7)*SPLITK + chunk*64;
    float4 zv = *reinterpret_cast<const float4*>(&zn[(size_t)row*DC + lane*4]);
    unsigned long long bk = ~0ull;
    for (int k = 0; k < 64; k += 4) {
      #pragma unroll
      for (int j = 0; j < 4; j++) {
        int code = c0 + k + j;
        float4 yv = *reinterpret_cast<const float4*>(&cn[(size_t)code*DC + lane*4]);
        float p = zv.x*yv.x + zv.y*yv.y + zv.z*yv.z + zv.w*yv.w;
        #pragma unroll
        for (int m = 1; m < 64; m <<= 1) p += __shfl_xor(p, m);
        unsigned long long key = pack_key(c2[code] - 2.f*p, code);
        bk = key < bk ? key : bk;
      }
    }
    if (lane == 0) atomicMin(&keys[row], bk);
  }
}

// ---------------- Kernel 3d: keys -> codes ----------------
__global__ __launch_bounds__(256) void k_final(const unsigned long long* __restrict__ keys,
                                               int* __restrict__ ci,
                                               float* __restrict__ cf) {
  int r = blockIdx.x*256 + threadIdx.x;
  int idx = (int)(keys[r] & 0xFFFFFFFFull);
  ci[r] = idx;
  cf[r] = (float)idx;
}

// ---------------- Kernel 4: q = gather(cbf) @ wqb^T via MFMA ----------------
__global__ __launch_bounds__(256, 2) void k_qgemm2(const int* __restrict__ ci,
                                                   const unsigned short* __restrict__ cbf,
                                                   const unsigned short* __restrict__ wqb,
                                                   float* __restrict__ qout) {
  __shared__ unsigned short Bs[64*256];
  const int tid  = threadIdx.x;
  const int lane = tid & 63;
  const int wv   = tid >> 6;
  const int lo   = lane & 15, hi = lane >> 4;
  const int rbw  = blockIdx.x * 256 + wv * 64;
  const int db   = blockIdx.y * 128;

  bf16x8 a[4][8];
  #pragma unroll
  for (int s = 0; s < 4; s++) {
    int code = ci[rbw + s*16 + lo];
    #pragma unroll
    for (int ks = 0; ks < 8; ks++)
      a[s][ks] = *reinterpret_cast<const bf16x8*>(&cbf[(size_t)code*DC + ks*32 + hi*8]);
  }
  #pragma unroll
  for (int s = 0; s < 4; s++)
    #pragma unroll
    for (int ks = 0; ks < 8; ks++)
      asm volatile("" : "+v"(a[s][ks]));

  int soff[8];
  #pragma unroll
  for (int i = 0; i < 8; i++) {
    int d = (wv*8 + i)*2 + (lane >> 5);
    int chg = (lane & 31) ^ (d & 7);
    soff[i] = d*512 + chg*16;
  }

  for (int t = 0; t < 2; t++) {
    const int dbx = db + t*64;
    __syncthreads();
    #pragma unroll
    for (int i = 0; i < 8; i++)
      gload_lds16((const char*)wqb + (size_t)dbx*512 + soff[i], (char*)Bs + (wv*8 + i)*1024);
    asm volatile("s_waitcnt vmcnt(0)" ::: "memory");
    __syncthreads();

    f32x4 acc[4][4];
    #pragma unroll
    for (int s = 0; s < 4; s++)
      #pragma unroll
      for (int cs = 0; cs < 4; cs++) acc[s][cs] = (f32x4){0.f,0.f,0.f,0.f};
    #pragma unroll
    for (int ks = 0; ks < 8; ks++) {
      const int chl = (ks*4 + hi) ^ (lo & 7);
      #pragma unroll
      for (int cs = 0; cs < 4; cs++) {
        bf16x8 b = *reinterpret_cast<const bf16x8*>(&Bs[(cs*16 + lo)*256 + chl*8]);
        #pragma unroll
        for (int s = 0; s < 4; s++)
          acc[s][cs] = __builtin_amdgcn_mfma_f32_16x16x32_bf16(a[s][ks], b, acc[s][cs], 0,0,0);
      }
    }
    #pragma unroll
    for (int s = 0; s < 4; s++)
      #pragma unroll
      for (int cs = 0; cs < 4; cs++)
        #pragma unroll
        for (int r = 0; r < 4; r++)
          qout[(size_t)(rbw + s*16 + hi*4 + r)*DIN + dbx + cs*16 + lo] = acc[s][cs][r];
  }
}

// ---------------- Kernel 5/6: quantize loss ----------------
__global__ __launch_bounds__(256) void k_losspart(const float* __restrict__ zn,
                                                  const float* __restrict__ cn,
                                                  const int* __restrict__ codes_i,
                                                  float* __restrict__ part) {
  const int tid = threadIdx.x;
  const size_t base = (size_t)blockIdx.x * 8192;
  float s = 0.f;
  #pragma unroll
  for (int k = 0; k < 32; k++) {
    size_t e = base + (size_t)k*256 + tid;
    int r = (int)(e >> 8);
    int c = (int)(e & 255);
    float d = cn[(size_t)codes_i[r]*DC + c] - zn[e];
    s += d * d;
  }
  #pragma unroll
  for (int m = 1; m < 64; m <<= 1) s += __shfl_xor(s, m);
  __shared__ float red[4];
  if ((tid & 63) == 0) red[tid >> 6] = s;
  __syncthreads();
  if (tid == 0) part[blockIdx.x] = (red[0] + red[1]) + (red[2] + red[3]);
}

__global__ __launch_bounds__(256) void k_lossfinal(const float* __restrict__ part,
                                                   float* __restrict__ loss_out) {
  const int tid = threadIdx.x;
  float s = part[tid] + part[tid + 256];
  #pragma unroll
  for (int m = 1; m < 64; m <<= 1) s += __shfl_xor(s, m);
  __shared__ float red[4];
  if ((tid & 63) == 0) red[tid >> 6] = s;
  __syncthreads();
  if (tid == 0) {
    float tot = (red[0] + red[1]) + (red[2] + red[3]);
    loss_out[0] = tot * 1.25f / 4194304.0f;
  }
}

extern "C" void kernel_launch(void* const* d_in, const int* in_sizes, int n_in,
                              void* d_out, int out_size, void* d_ws, size_t ws_size,
                              hipStream_t stream) {
  const float* z  = (const float*)d_in[0];
  const float* cb = (const float*)d_in[1];
  const float* wz = (const float*)d_in[2];
  const float* wq = (const float*)d_in[3];

  float* out = (float*)d_out;
  float* q_out   = out;
  float* codes_f = out + (size_t)R_TOT*DIN;
  float* loss_o  = codes_f + R_TOT;

  float* ws = (float*)d_ws;
  float* cn = ws + WS_CN;
  float* zn = ws + WS_ZN;
  float* c2 = ws + WS_C2;
  int*   ci = (int*)(ws + WS_CODES);
  float* pt = ws + WS_PART;
  unsigned short* cbf = (unsigned short*)(ws + WS_CBF);
  unsigned short* zbf = (unsigned short*)(ws + WS_ZBF);
  unsigned short* wh  = (unsigned short*)(ws + WS_WH);
  unsigned short* wl  = (unsigned short*)(ws + WS_WL);
  unsigned short* wqb = (unsigned short*)(ws + WS_WQB);
  unsigned* rmax = (unsigned*)(ws + WS_RMAX);
  unsigned* cntg = (unsigned*)(ws + WS_CNTG);
  unsigned* maskg = (unsigned*)(ws + WS_MASK);
  unsigned* candg = (unsigned*)(ws + WS_CANDG);
  unsigned long long* keys = (unsigned long long*)(ws + WS_KEYS);   // reuses WH
  unsigned* mlist = (unsigned*)(ws + WS_MLIST);                     // reuses WL

  // rmax, cntg, mask are contiguous: one memset
  hipMemsetAsync(rmax, 0, (size_t)3*R_TOT*sizeof(unsigned), stream);
  hipLaunchKernelGGL(k_codenorm, dim3(KCB), dim3(64), 0, stream, cb, cn, c2, cbf);
  hipLaunchKernelGGL(k_wprep, dim3(1024), dim3(256), 0, stream, wz, wq, wh, wl, wqb);
  hipLaunchKernelGGL(k_zlin2, dim3(R_TOT/64), dim3(512), 0, stream, z, wh, wl, zn, zbf);
  // wh/wl regions are dead after k_zlin2 -> reuse as keys/mlist
  hipMemsetAsync(mlist, 0, sizeof(unsigned), stream);
  hipLaunchKernelGGL(k_dist1, dim3((R_TOT/512)*DSPLIT), dim3(512), 0, stream,
                     zbf, cbf, rmax, cntg, candg, maskg);
  hipLaunchKernelGGL(k_refine, dim3(R_TOT/4), dim3(256), 0, stream,
                     zn, cn, c2, rmax, cntg, candg, maskg, keys, mlist, mlist);
  hipLaunchKernelGGL(k_maskscan, dim3(512), dim3(256), 0, stream,
                     zn, cn, c2, mlist, keys);
  hipLaunchKernelGGL(k_final, dim3(R_TOT/256), dim3(256), 0, stream, keys, ci, codes_f);
  hipLaunchKernelGGL(k_qgemm2, dim3(R_TOT/256, DIN/128), dim3(256), 0, stream, ci, cbf, wqb, q_out);
  hipLaunchKernelGGL(k_losspart, dim3(512), dim3(256), 0, stream, zn, cn, ci, pt);
  hipLaunchKernelGGL(k_lossfinal, dim3(1), dim3(256), 0, stream, pt, loss_o);
}